// Round 14
// baseline (328.139 us; speedup 1.0000x reference)
//
#include <hip/hip_runtime.h>

// ---------------------------------------------------------------------------
// RGCN (basis decomposition, 2 layers) + mean-pool.  v14 = v13 restructured:
//  - stride-9 xw layout: row r=0..7 relation products, row 8 = self+bias.
//    One skey=src*9+et serves both layers; agg buffers eliminated
//    (init = own row 8; seg2f accumulates into xw2 row 8 in place).
//  - k_f1 fuses seg1f+relu+xw2: h lives only in LDS (64 nodes/block).
//  - sort chain: weights folded into bhist; 3 scan kernels -> 1 strip-scan;
//    NBLK 256.  Launches 12 -> 8.
//
// ws layout (bytes):
//   W1f     us[8*4096]   @ 0          B-frags of W1 (bf16)
//   W2f     us[8*1024]   @ 65536
//   W1sf    us[4096]     @ 81920      wself1 frags
//   W2sf    us[1024]     @ 90112      wself2 frags
//   payload int[E]       @ 92160
//   skey    int[E]       @ 4092160    src*9+et, dst-sorted
//   nodeoff int[N+1]     @ 8092160
//   bh      int[nBins*256] @ 8492288
//   bhs     int[nBins*256] @ 8892672
//   xw1     us[N*9*64]   @ 9293056    (115.2 MB)
//   xw2     us[N*9*16]   @ 124493056  (28.8 MB; row 8 = final agg2)
// NEED ~153.3 MB (ws proven >= 166 MB in rounds 5-8)
// ---------------------------------------------------------------------------

typedef __attribute__((ext_vector_type(8))) short bf16x8;
typedef __attribute__((ext_vector_type(4))) float f32x4;

#define NBLK 256   // blocks for bucket counting sort

__device__ __forceinline__ unsigned short f2bf(float f) {
    unsigned u = __float_as_uint(f);
    unsigned r = u + 0x7FFFu + ((u >> 16) & 1u);   // RNE
    return (unsigned short)(r >> 16);
}

__device__ __forceinline__ float bf2f(unsigned short u) {
    return __uint_as_float(((unsigned)u) << 16);
}

__device__ __forceinline__ unsigned pk2(float lo, float hi) {
    unsigned r;
    asm("v_cvt_pk_bf16_f32 %0, %1, %2" : "=v"(r) : "v"(lo), "v"(hi));
    return r;
}

union cv16 { uint4 u; bf16x8 b; };

__device__ __forceinline__ void acc8(uint4 m, float* a) {
    a[0] += bf2f((unsigned short)m.x); a[1] += bf2f((unsigned short)(m.x >> 16));
    a[2] += bf2f((unsigned short)m.y); a[3] += bf2f((unsigned short)(m.y >> 16));
    a[4] += bf2f((unsigned short)m.z); a[5] += bf2f((unsigned short)(m.z >> 16));
    a[6] += bf2f((unsigned short)m.w); a[7] += bf2f((unsigned short)(m.w >> 16));
}

// ---- fused: blocks 0..NBLK-1 = dst>>8 histogram; blocks NBLK.. = weights
__global__ __launch_bounds__(256) void k_bhist_w(
    const int* __restrict__ dst, int* __restrict__ bh, int nE, int nBins,
    const float* __restrict__ bases1, const float* __restrict__ coeff1,
    const float* __restrict__ bases2, const float* __restrict__ coeff2,
    const float* __restrict__ wself1, const float* __restrict__ wself2,
    unsigned short* __restrict__ W1f, unsigned short* __restrict__ W2f,
    unsigned short* __restrict__ W1sf, unsigned short* __restrict__ W2sf) {
    if (blockIdx.x >= NBLK) {
        int r = blockIdx.x - NBLK;
        int tid = threadIdx.x;
        float c1[8], c2[8];
#pragma unroll
        for (int b = 0; b < 8; ++b) { c1[b] = coeff1[r * 8 + b]; c2[b] = coeff2[r * 8 + b]; }
        for (int idx = tid; idx < 4096; idx += 256) {
            int j = idx & 7, lane = (idx >> 3) & 63, nt = (idx >> 9) & 3, kt = idx >> 11;
            int i = kt * 32 + ((lane >> 4) << 3) + j;
            int jo = nt * 16 + (lane & 15);
            float s = 0.f;
#pragma unroll
            for (int b = 0; b < 8; ++b) s = fmaf(c1[b], bases1[b * 4096 + i * 64 + jo], s);
            W1f[r * 4096 + idx] = f2bf(s);
            if (r == 0) W1sf[idx] = f2bf(wself1[i * 64 + jo]);
        }
        for (int idx = tid; idx < 1024; idx += 256) {
            int j = idx & 7, lane = (idx >> 3) & 63, kt = idx >> 9;
            int i = kt * 32 + ((lane >> 4) << 3) + j;
            int jo = lane & 15;
            float s = 0.f;
#pragma unroll
            for (int b = 0; b < 8; ++b) s = fmaf(c2[b], bases2[b * 1024 + i * 16 + jo], s);
            W2f[r * 1024 + idx] = f2bf(s);
            if (r == 0) W2sf[idx] = f2bf(wself2[i * 16 + jo]);
        }
        return;
    }
    __shared__ int h[512];
    for (int i = threadIdx.x; i < 512; i += 256) h[i] = 0;
    __syncthreads();
    int blk = blockIdx.x;
    int ech = (nE + NBLK - 1) / NBLK;
    int e0 = blk * ech, e1 = min(e0 + ech, nE);
    for (int e = e0 + threadIdx.x; e < e1; e += 256)
        atomicAdd(&h[dst[e] >> 8], 1);
    __syncthreads();
    for (int t = threadIdx.x; t < nBins; t += 256) bh[t * NBLK + blk] = h[t];
}

// ---- single-block strip scan: bhs = exclusive prefix of bh (flat order)
__global__ __launch_bounds__(1024) void k_scan(
    const int* __restrict__ bh, int* __restrict__ bhs, int n) {
    __shared__ int tot[1024];
    int t = threadIdx.x;
    int S = (n + 1023) / 1024;
    int i0 = t * S, i1 = min(i0 + S, n);
    int s = 0;
    for (int i = i0; i < i1; ++i) s += bh[i];
    tot[t] = s;
    __syncthreads();
#pragma unroll
    for (int off = 1; off < 1024; off <<= 1) {
        int v = (t >= off) ? tot[t - off] : 0;
        __syncthreads();
        tot[t] += v;
        __syncthreads();
    }
    int run = tot[t] - s;   // exclusive base for this strip
    for (int i = i0; i < i1; ++i) { int d = bh[i]; bhs[i] = run; run += d; }
}

// ---- scatter payload into bucket order (LDS int cursors)
__global__ __launch_bounds__(256) void k_bscat(
    const int* __restrict__ dst, const int* __restrict__ src,
    const int* __restrict__ et, const int* __restrict__ bhs,
    int* __restrict__ payload, int nE, int nBins) {
    __shared__ int cur[512];
    int blk = blockIdx.x;
    for (int t = threadIdx.x; t < nBins; t += 256) cur[t] = bhs[t * NBLK + blk];
    __syncthreads();
    int ech = (nE + NBLK - 1) / NBLK;
    int e0 = blk * ech, e1 = min(e0 + ech, nE);
    for (int e = e0 + threadIdx.x; e < e1; e += 256) {
        int d = dst[e];
        int pos = atomicAdd(&cur[d >> 8], 1);
        payload[pos] = ((src[e] * 9 + et[e]) << 8) | (d & 255);
    }
}

// ---- per-bucket refine -> per-node CSR (skey, nodeoff)
__global__ __launch_bounds__(256) void k_brefine(
    const int* __restrict__ payload, const int* __restrict__ bhs,
    int* __restrict__ skey, int* __restrict__ nodeoff,
    int nE, int nBins, int nNodes) {
    __shared__ int h[256];
    __shared__ int cur[256];
    __shared__ int sm[256];
    int b = blockIdx.x;
    int e0 = bhs[b * NBLK];
    int e1 = (b + 1 < nBins) ? bhs[(b + 1) * NBLK] : nE;
    int t = threadIdx.x;
    h[t] = 0;
    __syncthreads();
    for (int e = e0 + t; e < e1; e += 256)
        atomicAdd(&h[payload[e] & 255], 1);
    __syncthreads();
    int d = h[t];
    sm[t] = d;
    __syncthreads();
#pragma unroll
    for (int off = 1; off < 256; off <<= 1) {
        int v = (t >= off) ? sm[t - off] : 0;
        __syncthreads();
        sm[t] += v;
        __syncthreads();
    }
    int excl = sm[t] - d;
    cur[t] = excl;
    int n = (b << 8) + t;
    if (n < nNodes) nodeoff[n] = e0 + excl;
    __syncthreads();
    for (int e = e0 + t; e < e1; e += 256) {
        int pay = payload[e];
        int pos = atomicAdd(&cur[pay & 255], 1);
        skey[e0 + pos] = pay >> 8;
    }
    if (b == 0 && t == 0) nodeoff[nNodes] = nE;
}

// ---- xw1[(n*9+r)*64] = bf16( x[n] @ W_r ), r=0..7; row 8 = x@wself1+bias1
#define XW1S 44
__global__ __launch_bounds__(256) void k_xw1(
    const float* __restrict__ x,
    const unsigned short* __restrict__ W1f,
    const unsigned short* __restrict__ W1sf,
    const float* __restrict__ bias1,
    unsigned short* __restrict__ xw1, int nNodes) {
    __shared__ unsigned lds[4][16 * XW1S];
    int lane = threadIdx.x & 63;
    int wid = (int)(threadIdx.x >> 6);
    int tile = blockIdx.x * 4 + wid;
    int n0 = tile * 16;
    if (n0 >= nNodes) return;
    int sA = n0 + (lane & 15);
    if (sA >= nNodes) sA = nNodes - 1;
    const float* xrow = x + (size_t)sA * 64 + ((lane >> 4) << 3);
    bf16x8 a[2];
#pragma unroll
    for (int kt = 0; kt < 2; ++kt) {
        f32x4 u0 = *(const f32x4*)(xrow + kt * 32);
        f32x4 u1 = *(const f32x4*)(xrow + kt * 32 + 4);
        cv16 c;
        c.u.x = pk2(u0[0], u0[1]);
        c.u.y = pk2(u0[2], u0[3]);
        c.u.z = pk2(u1[0], u1[1]);
        c.u.w = pk2(u1[2], u1[3]);
        a[kt] = c.b;
    }
    float bj[4];
#pragma unroll
    for (int nt = 0; nt < 4; ++nt) bj[nt] = bias1[nt * 16 + (lane & 15)];
    unsigned* L = lds[wid];
    const int even = !(lane & 1);
    const int cpair = (lane & 14) >> 1;
    int row2 = lane >> 2, ch = lane & 3;
    int nOut = n0 + row2;
    for (int r = 0; r < 9; ++r) {
        const unsigned short* Wf = (r < 8) ? (W1f + r * 4096) : W1sf;
        f32x4 z = {0.f, 0.f, 0.f, 0.f};
        f32x4 acc[4] = {z, z, z, z};
#pragma unroll
        for (int kt = 0; kt < 2; ++kt)
#pragma unroll
            for (int nt = 0; nt < 4; ++nt) {
                bf16x8 b = *(const bf16x8*)(Wf + (kt * 4 + nt) * 512 + lane * 8);
                acc[nt] = __builtin_amdgcn_mfma_f32_16x16x32_bf16(a[kt], b, acc[nt], 0, 0, 0);
            }
        if (r == 8) {
#pragma unroll
            for (int nt = 0; nt < 4; ++nt)
#pragma unroll
                for (int reg = 0; reg < 4; ++reg) acc[nt][reg] += bj[nt];
        }
#pragma unroll
        for (int reg = 0; reg < 4; ++reg) {
            int row = ((lane >> 4) << 2) + reg;
#pragma unroll
            for (int nt = 0; nt < 4; ++nt) {
                float mine = acc[nt][reg];
                float oth = __shfl_xor(mine, 1, 64);
                unsigned pk = even ? pk2(mine, oth) : pk2(oth, mine);
                if (even ? (nt < 2) : (nt >= 2)) L[row * XW1S + cpair + nt * 8] = pk;
            }
        }
        if (nOut < nNodes) {
            uint4 v0 = *(uint4*)&L[row2 * XW1S + ch * 4];
            uint4 v1 = *(uint4*)&L[row2 * XW1S + 16 + ch * 4];
            uint4* mp = (uint4*)(xw1 + ((size_t)nOut * 9 + r) * 64);
            mp[ch] = v0;
            mp[4 + ch] = v1;
        }
    }
}

// ---- fused: gather+segsum+relu (h in LDS) then xw2 MFMA; 64 nodes/block
__global__ __launch_bounds__(256) void k_f1(
    const unsigned short* __restrict__ xw1, const int* __restrict__ skey,
    const int* __restrict__ nodeoff,
    const unsigned short* __restrict__ W2f,
    const unsigned short* __restrict__ W2sf,
    const float* __restrict__ bias2,
    unsigned short* __restrict__ xw2, int nNodes) {
    __shared__ uint4 hbuf[64][9];            // [node][colblk], +1 pad
    __shared__ unsigned tlds[4][16 * 12];
    int t = threadIdx.x;
    int n0blk = blockIdx.x * 64;
    int gl = t & 7;
    int grp = t >> 3;                        // 0..31
    for (int pass = 0; pass < 2; ++pass) {
        int nn = pass * 32 + grp;
        int n = n0blk + nn;
        uint4 p = {0, 0, 0, 0};
        if (n < nNodes) {
            int s0 = nodeoff[n], s1 = nodeoff[n + 1];
            uint4 v = *(const uint4*)(xw1 + ((size_t)n * 9 + 8) * 64 + gl * 8);
            float a[8];
            a[0] = bf2f((unsigned short)v.x); a[1] = bf2f((unsigned short)(v.x >> 16));
            a[2] = bf2f((unsigned short)v.y); a[3] = bf2f((unsigned short)(v.y >> 16));
            a[4] = bf2f((unsigned short)v.z); a[5] = bf2f((unsigned short)(v.z >> 16));
            a[6] = bf2f((unsigned short)v.w); a[7] = bf2f((unsigned short)(v.w >> 16));
            int i = s0;
            for (; i + 4 <= s1; i += 4) {
                int k0 = skey[i], k1 = skey[i + 1], k2 = skey[i + 2], k3 = skey[i + 3];
                uint4 m0 = *(const uint4*)(xw1 + (size_t)k0 * 64 + gl * 8);
                uint4 m1 = *(const uint4*)(xw1 + (size_t)k1 * 64 + gl * 8);
                uint4 m2 = *(const uint4*)(xw1 + (size_t)k2 * 64 + gl * 8);
                uint4 m3 = *(const uint4*)(xw1 + (size_t)k3 * 64 + gl * 8);
                acc8(m0, a); acc8(m1, a); acc8(m2, a); acc8(m3, a);
            }
            for (; i < s1; ++i) {
                uint4 m = *(const uint4*)(xw1 + (size_t)skey[i] * 64 + gl * 8);
                acc8(m, a);
            }
#pragma unroll
            for (int q = 0; q < 8; ++q) a[q] = fmaxf(a[q], 0.f);   // relu -> h
            p.x = pk2(a[0], a[1]);
            p.y = pk2(a[2], a[3]);
            p.z = pk2(a[4], a[5]);
            p.w = pk2(a[6], a[7]);
        }
        hbuf[nn][gl] = p;
    }
    __syncthreads();
    // phase B: wave w -> 16-node tile w
    int lane = t & 63;
    int w = t >> 6;
    int arow = w * 16 + (lane & 15);
    cv16 c0, c1;
    c0.u = hbuf[arow][lane >> 4];
    c1.u = hbuf[arow][4 + (lane >> 4)];
    bf16x8 a0 = c0.b, a1 = c1.b;
    float bj = bias2[lane & 15];
    unsigned* L = tlds[w];
    const int even = !(lane & 1);
    const int cpair = (lane & 14) >> 1;
    int row2 = lane >> 1, ch = lane & 1;
    int nOut = n0blk + w * 16 + row2;
    for (int r = 0; r < 9; ++r) {
        const unsigned short* Wf = (r < 8) ? (W2f + r * 1024) : W2sf;
        bf16x8 b0 = *(const bf16x8*)(Wf + lane * 8);
        bf16x8 b1 = *(const bf16x8*)(Wf + 512 + lane * 8);
        f32x4 acc = {0.f, 0.f, 0.f, 0.f};
        acc = __builtin_amdgcn_mfma_f32_16x16x32_bf16(a0, b0, acc, 0, 0, 0);
        acc = __builtin_amdgcn_mfma_f32_16x16x32_bf16(a1, b1, acc, 0, 0, 0);
        if (r == 8) {
#pragma unroll
            for (int reg = 0; reg < 4; ++reg) acc[reg] += bj;
        }
#pragma unroll
        for (int reg = 0; reg < 4; ++reg) {
            int row = ((lane >> 4) << 2) + reg;
            float mine = acc[reg];
            float oth = __shfl_xor(mine, 1, 64);
            unsigned pk = even ? pk2(mine, oth) : pk2(oth, mine);
            if (even ? (reg < 2) : (reg >= 2)) L[row * 12 + cpair] = pk;
        }
        if (lane < 32 && nOut < nNodes) {
            uint4 v = *(uint4*)&L[row2 * 12 + ch * 4];
            ((uint4*)(xw2 + ((size_t)nOut * 9 + r) * 16))[ch] = v;
        }
    }
}

// ---- layer2 gather+segsum, in place into xw2 row 8 (2-lane group, unroll-4)
__global__ __launch_bounds__(256) void k_seg2f(
    unsigned short* __restrict__ xw2, const int* __restrict__ skey,
    const int* __restrict__ nodeoff, int nNodes) {
    int gl = threadIdx.x & 1;
    int grp = (int)((blockIdx.x * blockDim.x + threadIdx.x) >> 1);
    int nG = (int)((gridDim.x * blockDim.x) >> 1);
    for (int n = grp; n < nNodes; n += nG) {
        int s0 = nodeoff[n], s1 = nodeoff[n + 1];
        uint4 v = *(const uint4*)(xw2 + ((size_t)n * 9 + 8) * 16 + gl * 8);
        float a[8];
        a[0] = bf2f((unsigned short)v.x); a[1] = bf2f((unsigned short)(v.x >> 16));
        a[2] = bf2f((unsigned short)v.y); a[3] = bf2f((unsigned short)(v.y >> 16));
        a[4] = bf2f((unsigned short)v.z); a[5] = bf2f((unsigned short)(v.z >> 16));
        a[6] = bf2f((unsigned short)v.w); a[7] = bf2f((unsigned short)(v.w >> 16));
        int i = s0;
        for (; i + 4 <= s1; i += 4) {
            int k0 = skey[i], k1 = skey[i + 1], k2 = skey[i + 2], k3 = skey[i + 3];
            uint4 m0 = *(const uint4*)(xw2 + (size_t)k0 * 16 + gl * 8);
            uint4 m1 = *(const uint4*)(xw2 + (size_t)k1 * 16 + gl * 8);
            uint4 m2 = *(const uint4*)(xw2 + (size_t)k2 * 16 + gl * 8);
            uint4 m3 = *(const uint4*)(xw2 + (size_t)k3 * 16 + gl * 8);
            acc8(m0, a); acc8(m1, a); acc8(m2, a); acc8(m3, a);
        }
        for (; i < s1; ++i) {
            uint4 m = *(const uint4*)(xw2 + (size_t)skey[i] * 16 + gl * 8);
            acc8(m, a);
        }
        uint4 p;
        p.x = pk2(a[0], a[1]);
        p.y = pk2(a[2], a[3]);
        p.z = pk2(a[4], a[5]);
        p.w = pk2(a[6], a[7]);
        *(uint4*)(xw2 + ((size_t)n * 9 + 8) * 16 + gl * 8) = p;
    }
}

// ---- mean-pool (reads xw2 row 8) with fused boundary binary search
__global__ __launch_bounds__(256) void k_pool(
    const unsigned short* __restrict__ xw2, const int* __restrict__ gid,
    float* __restrict__ out, int nNodes) {
    __shared__ float sm[256];
    __shared__ int bnd[2];
    int g = blockIdx.x;
    int t = threadIdx.x;
    if (t < 2) {
        int target = g + t;
        int lo = 0, hi = nNodes;
        while (lo < hi) {
            int mid = (lo + hi) >> 1;
            if (gid[mid] < target) lo = mid + 1; else hi = mid;
        }
        bnd[t] = lo;
    }
    __syncthreads();
    int s0 = bnd[0], s1 = bnd[1];
    int c = t & 15, idx = t >> 4;
    float acc = 0.f;
    for (int n = s0 + idx; n < s1; n += 16)
        acc += fmaxf(bf2f(xw2[((size_t)n * 9 + 8) * 16 + c]), 0.f);
    sm[t] = acc;
    __syncthreads();
#pragma unroll
    for (int off = 128; off >= 16; off >>= 1) {
        if (t < off) sm[t] += sm[t + off];
        __syncthreads();
    }
    if (t < 16) {
        float cnt = (float)(s1 - s0);
        out[g * 16 + t] = sm[t] / fmaxf(cnt, 1.f);
    }
}

extern "C" void kernel_launch(void* const* d_in, const int* in_sizes, int n_in,
                              void* d_out, int out_size, void* d_ws, size_t ws_size,
                              hipStream_t stream) {
    const float* x      = (const float*)d_in[0];
    const int*   src    = (const int*)d_in[1];
    const int*   dst    = (const int*)d_in[2];
    const int*   et     = (const int*)d_in[3];
    const int*   gid    = (const int*)d_in[4];
    const float* bases1 = (const float*)d_in[5];
    const float* coeff1 = (const float*)d_in[6];
    const float* wself1 = (const float*)d_in[7];
    const float* bias1  = (const float*)d_in[8];
    const float* bases2 = (const float*)d_in[9];
    const float* coeff2 = (const float*)d_in[10];
    const float* wself2 = (const float*)d_in[11];
    const float* bias2  = (const float*)d_in[12];
    float* out = (float*)d_out;

    int nNodes = in_sizes[0] / 64;
    int nE = in_sizes[1];
    int nBins = (nNodes + 255) >> 8;
    int nBh = nBins * NBLK;

    char* ws = (char*)d_ws;
    unsigned short* W1f  = (unsigned short*)(ws);
    unsigned short* W2f  = (unsigned short*)(ws + 65536);
    unsigned short* W1sf = (unsigned short*)(ws + 81920);
    unsigned short* W2sf = (unsigned short*)(ws + 90112);
    int*   payload = (int*)(ws + 92160);
    int*   skey    = (int*)(ws + 4092160);
    int*   nodeoff = (int*)(ws + 8092160);
    int*   bh      = (int*)(ws + 8492288);
    int*   bhs     = (int*)(ws + 8892672);
    unsigned short* xw1 = (unsigned short*)(ws + 9293056);
    unsigned short* xw2 = (unsigned short*)(ws + 124493056);

    int tiles = (nNodes + 15) / 16;
    int xwb = (tiles + 3) / 4;
    int f1b = (nNodes + 63) / 64;

    hipLaunchKernelGGL(k_bhist_w, dim3(NBLK + 8), dim3(256), 0, stream,
                       dst, bh, nE, nBins,
                       bases1, coeff1, bases2, coeff2, wself1, wself2,
                       W1f, W2f, W1sf, W2sf);
    hipLaunchKernelGGL(k_scan, dim3(1), dim3(1024), 0, stream, bh, bhs, nBh);
    hipLaunchKernelGGL(k_bscat, dim3(NBLK), dim3(256), 0, stream,
                       dst, src, et, bhs, payload, nE, nBins);
    hipLaunchKernelGGL(k_brefine, dim3(nBins), dim3(256), 0, stream,
                       payload, bhs, skey, nodeoff, nE, nBins, nNodes);
    hipLaunchKernelGGL(k_xw1, dim3(xwb), dim3(256), 0, stream,
                       x, W1f, W1sf, bias1, xw1, nNodes);
    hipLaunchKernelGGL(k_f1, dim3(f1b), dim3(256), 0, stream,
                       xw1, skey, nodeoff, W2f, W2sf, bias2, xw2, nNodes);
    hipLaunchKernelGGL(k_seg2f, dim3(1024), dim3(256), 0, stream,
                       xw2, skey, nodeoff, nNodes);
    hipLaunchKernelGGL(k_pool, dim3(64), dim3(256), 0, stream,
                       xw2, gid, out, nNodes);
}

// Round 16
// 177.118 us; speedup vs baseline: 1.8527x; 1.8527x over previous
//
#include <hip/hip_runtime.h>

// ---------------------------------------------------------------------------
// RGCN (basis decomposition, 2 layers) + mean-pool.  v16 = v15 with the
// workspace layout bug fixed (bhs needs 400384 B; btot had been placed 256 B
// too early, corrupting the scan -> OOB scatter -> abort).
//  - stride-9 xw layout (row 8 = self+bias; one skey serves both layers)
//  - k_f1 fuses seg1+relu+xw2 (h lives in LDS only)
//  - weights folded into bhist launch; proven 3-kernel scan chain
//
// ws layout (bytes):
//   W1f     us[8*4096]   @ 0          B-frags of W1 (bf16)
//   W2f     us[8*1024]   @ 65536
//   W1sf    us[4096]     @ 81920      wself1 frags
//   W2sf    us[1024]     @ 90112      wself2 frags
//   payload int[E]       @ 92160
//   skey    int[E]       @ 4092160    src*9+et, dst-sorted
//   nodeoff int[N+1]     @ 8092160
//   bh      int[nBh]     @ 8492288    (nBh = nBins*256 = 100096 -> 400384 B)
//   bhs     int[nBh]     @ 8892672    (400384 B)
//   btot    int[512]     @ 9293056
//   boff    int[512]     @ 9295104
//   xw1     us[N*9*64]   @ 9297152    (115.2 MB)
//   xw2     us[N*9*16]   @ 124497152  (28.8 MB; row 8 = final agg2)
// NEED ~153.3 MB (ws proven >= 166 MB in rounds 5-8)
// ---------------------------------------------------------------------------

typedef __attribute__((ext_vector_type(8))) short bf16x8;
typedef __attribute__((ext_vector_type(4))) float f32x4;

#define NBLK 256   // blocks for bucket counting sort

__device__ __forceinline__ unsigned short f2bf(float f) {
    unsigned u = __float_as_uint(f);
    unsigned r = u + 0x7FFFu + ((u >> 16) & 1u);   // RNE
    return (unsigned short)(r >> 16);
}

__device__ __forceinline__ float bf2f(unsigned short u) {
    return __uint_as_float(((unsigned)u) << 16);
}

__device__ __forceinline__ unsigned pk2(float lo, float hi) {
    unsigned r;
    asm("v_cvt_pk_bf16_f32 %0, %1, %2" : "=v"(r) : "v"(lo), "v"(hi));
    return r;
}

union cv16 { uint4 u; bf16x8 b; };

__device__ __forceinline__ void acc8(uint4 m, float* a) {
    a[0] += bf2f((unsigned short)m.x); a[1] += bf2f((unsigned short)(m.x >> 16));
    a[2] += bf2f((unsigned short)m.y); a[3] += bf2f((unsigned short)(m.y >> 16));
    a[4] += bf2f((unsigned short)m.z); a[5] += bf2f((unsigned short)(m.z >> 16));
    a[6] += bf2f((unsigned short)m.w); a[7] += bf2f((unsigned short)(m.w >> 16));
}

// ---- fused: blocks 0..NBLK-1 = dst>>8 histogram; blocks NBLK.. = weights
__global__ __launch_bounds__(256) void k_bhist_w(
    const int* __restrict__ dst, int* __restrict__ bh, int nE, int nBins,
    const float* __restrict__ bases1, const float* __restrict__ coeff1,
    const float* __restrict__ bases2, const float* __restrict__ coeff2,
    const float* __restrict__ wself1, const float* __restrict__ wself2,
    unsigned short* __restrict__ W1f, unsigned short* __restrict__ W2f,
    unsigned short* __restrict__ W1sf, unsigned short* __restrict__ W2sf) {
    if (blockIdx.x >= NBLK) {
        int r = blockIdx.x - NBLK;
        int tid = threadIdx.x;
        float c1[8], c2[8];
#pragma unroll
        for (int b = 0; b < 8; ++b) { c1[b] = coeff1[r * 8 + b]; c2[b] = coeff2[r * 8 + b]; }
        for (int idx = tid; idx < 4096; idx += 256) {
            int j = idx & 7, lane = (idx >> 3) & 63, nt = (idx >> 9) & 3, kt = idx >> 11;
            int i = kt * 32 + ((lane >> 4) << 3) + j;
            int jo = nt * 16 + (lane & 15);
            float s = 0.f;
#pragma unroll
            for (int b = 0; b < 8; ++b) s = fmaf(c1[b], bases1[b * 4096 + i * 64 + jo], s);
            W1f[r * 4096 + idx] = f2bf(s);
            if (r == 0) W1sf[idx] = f2bf(wself1[i * 64 + jo]);
        }
        for (int idx = tid; idx < 1024; idx += 256) {
            int j = idx & 7, lane = (idx >> 3) & 63, kt = idx >> 9;
            int i = kt * 32 + ((lane >> 4) << 3) + j;
            int jo = lane & 15;
            float s = 0.f;
#pragma unroll
            for (int b = 0; b < 8; ++b) s = fmaf(c2[b], bases2[b * 1024 + i * 16 + jo], s);
            W2f[r * 1024 + idx] = f2bf(s);
            if (r == 0) W2sf[idx] = f2bf(wself2[i * 16 + jo]);
        }
        return;
    }
    __shared__ int h[512];
    for (int i = threadIdx.x; i < 512; i += 256) h[i] = 0;
    __syncthreads();
    int blk = blockIdx.x;
    int ech = (nE + NBLK - 1) / NBLK;
    int e0 = blk * ech, e1 = min(e0 + ech, nE);
    for (int e = e0 + threadIdx.x; e < e1; e += 256)
        atomicAdd(&h[dst[e] >> 8], 1);
    __syncthreads();
    for (int t = threadIdx.x; t < nBins; t += 256) bh[t * NBLK + blk] = h[t];
}

// ---- proven 3-kernel scan chain (coalesced, multi-CU)
__global__ __launch_bounds__(256) void k_scanblk(
    const int* __restrict__ in, int* __restrict__ outx,
    int* __restrict__ btot, int n) {
    __shared__ int sm[256];
    int tid = threadIdx.x;
    int i = blockIdx.x * 256 + tid;
    int d = (i < n) ? in[i] : 0;
    sm[tid] = d;
    __syncthreads();
#pragma unroll
    for (int off = 1; off < 256; off <<= 1) {
        int v = (tid >= off) ? sm[tid - off] : 0;
        __syncthreads();
        sm[tid] += v;
        __syncthreads();
    }
    if (i < n) outx[i] = sm[tid] - d;
    if (tid == 255) btot[blockIdx.x] = sm[255];
}

__global__ void k_scantop(const int* __restrict__ btot, int* __restrict__ boff, int nB) {
    __shared__ int sm[512];
    int t = threadIdx.x;
    int d = (t < nB) ? btot[t] : 0;
    sm[t] = d;
    __syncthreads();
#pragma unroll
    for (int off = 1; off < 512; off <<= 1) {
        int v = (t >= off) ? sm[t - off] : 0;
        __syncthreads();
        sm[t] += v;
        __syncthreads();
    }
    if (t < nB) boff[t] = sm[t] - d;
}

__global__ __launch_bounds__(256) void k_scanadd2(
    int* __restrict__ bhs, const int* __restrict__ boff, int n) {
    int i = blockIdx.x * 256 + threadIdx.x;
    if (i < n) bhs[i] += boff[i >> 8];
}

// ---- scatter payload into bucket order (LDS int cursors)
__global__ __launch_bounds__(256) void k_bscat(
    const int* __restrict__ dst, const int* __restrict__ src,
    const int* __restrict__ et, const int* __restrict__ bhs,
    int* __restrict__ payload, int nE, int nBins) {
    __shared__ int cur[512];
    int blk = blockIdx.x;
    for (int t = threadIdx.x; t < nBins; t += 256) cur[t] = bhs[t * NBLK + blk];
    __syncthreads();
    int ech = (nE + NBLK - 1) / NBLK;
    int e0 = blk * ech, e1 = min(e0 + ech, nE);
    for (int e = e0 + threadIdx.x; e < e1; e += 256) {
        int d = dst[e];
        int pos = atomicAdd(&cur[d >> 8], 1);
        payload[pos] = ((src[e] * 9 + et[e]) << 8) | (d & 255);
    }
}

// ---- per-bucket refine -> per-node CSR (skey, nodeoff)
__global__ __launch_bounds__(256) void k_brefine(
    const int* __restrict__ payload, const int* __restrict__ bhs,
    int* __restrict__ skey, int* __restrict__ nodeoff,
    int nE, int nBins, int nNodes) {
    __shared__ int h[256];
    __shared__ int cur[256];
    __shared__ int sm[256];
    int b = blockIdx.x;
    int e0 = bhs[b * NBLK];
    int e1 = (b + 1 < nBins) ? bhs[(b + 1) * NBLK] : nE;
    int t = threadIdx.x;
    h[t] = 0;
    __syncthreads();
    for (int e = e0 + t; e < e1; e += 256)
        atomicAdd(&h[payload[e] & 255], 1);
    __syncthreads();
    int d = h[t];
    sm[t] = d;
    __syncthreads();
#pragma unroll
    for (int off = 1; off < 256; off <<= 1) {
        int v = (t >= off) ? sm[t - off] : 0;
        __syncthreads();
        sm[t] += v;
        __syncthreads();
    }
    int excl = sm[t] - d;
    cur[t] = excl;
    int n = (b << 8) + t;
    if (n < nNodes) nodeoff[n] = e0 + excl;
    __syncthreads();
    for (int e = e0 + t; e < e1; e += 256) {
        int pay = payload[e];
        int pos = atomicAdd(&cur[pay & 255], 1);
        skey[e0 + pos] = pay >> 8;
    }
    if (b == 0 && t == 0) nodeoff[nNodes] = nE;
}

// ---- xw1[(n*9+r)*64] = bf16( x[n] @ W_r ), r=0..7; row 8 = x@wself1+bias1
#define XW1S 44
__global__ __launch_bounds__(256) void k_xw1(
    const float* __restrict__ x,
    const unsigned short* __restrict__ W1f,
    const unsigned short* __restrict__ W1sf,
    const float* __restrict__ bias1,
    unsigned short* __restrict__ xw1, int nNodes) {
    __shared__ unsigned lds[4][16 * XW1S];
    int lane = threadIdx.x & 63;
    int wid = (int)(threadIdx.x >> 6);
    int tile = blockIdx.x * 4 + wid;
    int n0 = tile * 16;
    if (n0 >= nNodes) return;
    int sA = n0 + (lane & 15);
    if (sA >= nNodes) sA = nNodes - 1;
    const float* xrow = x + (size_t)sA * 64 + ((lane >> 4) << 3);
    bf16x8 a[2];
#pragma unroll
    for (int kt = 0; kt < 2; ++kt) {
        f32x4 u0 = *(const f32x4*)(xrow + kt * 32);
        f32x4 u1 = *(const f32x4*)(xrow + kt * 32 + 4);
        cv16 c;
        c.u.x = pk2(u0[0], u0[1]);
        c.u.y = pk2(u0[2], u0[3]);
        c.u.z = pk2(u1[0], u1[1]);
        c.u.w = pk2(u1[2], u1[3]);
        a[kt] = c.b;
    }
    float bj[4];
#pragma unroll
    for (int nt = 0; nt < 4; ++nt) bj[nt] = bias1[nt * 16 + (lane & 15)];
    unsigned* L = lds[wid];
    const int even = !(lane & 1);
    const int cpair = (lane & 14) >> 1;
    int row2 = lane >> 2, ch = lane & 3;
    int nOut = n0 + row2;
    for (int r = 0; r < 9; ++r) {
        const unsigned short* Wf = (r < 8) ? (W1f + r * 4096) : W1sf;
        f32x4 z = {0.f, 0.f, 0.f, 0.f};
        f32x4 acc[4] = {z, z, z, z};
#pragma unroll
        for (int kt = 0; kt < 2; ++kt)
#pragma unroll
            for (int nt = 0; nt < 4; ++nt) {
                bf16x8 b = *(const bf16x8*)(Wf + (kt * 4 + nt) * 512 + lane * 8);
                acc[nt] = __builtin_amdgcn_mfma_f32_16x16x32_bf16(a[kt], b, acc[nt], 0, 0, 0);
            }
        if (r == 8) {
#pragma unroll
            for (int nt = 0; nt < 4; ++nt)
#pragma unroll
                for (int reg = 0; reg < 4; ++reg) acc[nt][reg] += bj[nt];
        }
#pragma unroll
        for (int reg = 0; reg < 4; ++reg) {
            int row = ((lane >> 4) << 2) + reg;
#pragma unroll
            for (int nt = 0; nt < 4; ++nt) {
                float mine = acc[nt][reg];
                float oth = __shfl_xor(mine, 1, 64);
                unsigned pk = even ? pk2(mine, oth) : pk2(oth, mine);
                if (even ? (nt < 2) : (nt >= 2)) L[row * XW1S + cpair + nt * 8] = pk;
            }
        }
        if (nOut < nNodes) {
            uint4 v0 = *(uint4*)&L[row2 * XW1S + ch * 4];
            uint4 v1 = *(uint4*)&L[row2 * XW1S + 16 + ch * 4];
            uint4* mp = (uint4*)(xw1 + ((size_t)nOut * 9 + r) * 64);
            mp[ch] = v0;
            mp[4 + ch] = v1;
        }
    }
}

// ---- fused: gather+segsum+relu (h in LDS) then xw2 MFMA; 64 nodes/block
__global__ __launch_bounds__(256) void k_f1(
    const unsigned short* __restrict__ xw1, const int* __restrict__ skey,
    const int* __restrict__ nodeoff,
    const unsigned short* __restrict__ W2f,
    const unsigned short* __restrict__ W2sf,
    const float* __restrict__ bias2,
    unsigned short* __restrict__ xw2, int nNodes) {
    __shared__ uint4 hbuf[64][9];            // [node][colblk], +1 pad
    __shared__ unsigned tlds[4][16 * 12];
    int t = threadIdx.x;
    int n0blk = blockIdx.x * 64;
    int gl = t & 7;
    int grp = t >> 3;                        // 0..31
    for (int pass = 0; pass < 2; ++pass) {
        int nn = pass * 32 + grp;
        int n = n0blk + nn;
        uint4 p = {0, 0, 0, 0};
        if (n < nNodes) {
            int s0 = nodeoff[n], s1 = nodeoff[n + 1];
            uint4 v = *(const uint4*)(xw1 + ((size_t)n * 9 + 8) * 64 + gl * 8);
            float a[8];
            a[0] = bf2f((unsigned short)v.x); a[1] = bf2f((unsigned short)(v.x >> 16));
            a[2] = bf2f((unsigned short)v.y); a[3] = bf2f((unsigned short)(v.y >> 16));
            a[4] = bf2f((unsigned short)v.z); a[5] = bf2f((unsigned short)(v.z >> 16));
            a[6] = bf2f((unsigned short)v.w); a[7] = bf2f((unsigned short)(v.w >> 16));
            int i = s0;
            for (; i + 4 <= s1; i += 4) {
                int k0 = skey[i], k1 = skey[i + 1], k2 = skey[i + 2], k3 = skey[i + 3];
                uint4 m0 = *(const uint4*)(xw1 + (size_t)k0 * 64 + gl * 8);
                uint4 m1 = *(const uint4*)(xw1 + (size_t)k1 * 64 + gl * 8);
                uint4 m2 = *(const uint4*)(xw1 + (size_t)k2 * 64 + gl * 8);
                uint4 m3 = *(const uint4*)(xw1 + (size_t)k3 * 64 + gl * 8);
                acc8(m0, a); acc8(m1, a); acc8(m2, a); acc8(m3, a);
            }
            for (; i < s1; ++i) {
                uint4 m = *(const uint4*)(xw1 + (size_t)skey[i] * 64 + gl * 8);
                acc8(m, a);
            }
#pragma unroll
            for (int q = 0; q < 8; ++q) a[q] = fmaxf(a[q], 0.f);   // relu -> h
            p.x = pk2(a[0], a[1]);
            p.y = pk2(a[2], a[3]);
            p.z = pk2(a[4], a[5]);
            p.w = pk2(a[6], a[7]);
        }
        hbuf[nn][gl] = p;
    }
    __syncthreads();
    // phase B: wave w -> 16-node tile w
    int lane = t & 63;
    int w = t >> 6;
    int arow = w * 16 + (lane & 15);
    cv16 c0, c1;
    c0.u = hbuf[arow][lane >> 4];
    c1.u = hbuf[arow][4 + (lane >> 4)];
    bf16x8 a0 = c0.b, a1 = c1.b;
    float bj = bias2[lane & 15];
    unsigned* L = tlds[w];
    const int even = !(lane & 1);
    const int cpair = (lane & 14) >> 1;
    int row2 = lane >> 1, ch = lane & 1;
    int nOut = n0blk + w * 16 + row2;
    for (int r = 0; r < 9; ++r) {
        const unsigned short* Wf = (r < 8) ? (W2f + r * 1024) : W2sf;
        bf16x8 b0 = *(const bf16x8*)(Wf + lane * 8);
        bf16x8 b1 = *(const bf16x8*)(Wf + 512 + lane * 8);
        f32x4 acc = {0.f, 0.f, 0.f, 0.f};
        acc = __builtin_amdgcn_mfma_f32_16x16x32_bf16(a0, b0, acc, 0, 0, 0);
        acc = __builtin_amdgcn_mfma_f32_16x16x32_bf16(a1, b1, acc, 0, 0, 0);
        if (r == 8) {
#pragma unroll
            for (int reg = 0; reg < 4; ++reg) acc[reg] += bj;
        }
#pragma unroll
        for (int reg = 0; reg < 4; ++reg) {
            int row = ((lane >> 4) << 2) + reg;
            float mine = acc[reg];
            float oth = __shfl_xor(mine, 1, 64);
            unsigned pk = even ? pk2(mine, oth) : pk2(oth, mine);
            if (even ? (reg < 2) : (reg >= 2)) L[row * 12 + cpair] = pk;
        }
        if (lane < 32 && nOut < nNodes) {
            uint4 v = *(uint4*)&L[row2 * 12 + ch * 4];
            ((uint4*)(xw2 + ((size_t)nOut * 9 + r) * 16))[ch] = v;
        }
    }
}

// ---- layer2 gather+segsum, in place into xw2 row 8 (2-lane group, unroll-4)
__global__ __launch_bounds__(256) void k_seg2f(
    unsigned short* __restrict__ xw2, const int* __restrict__ skey,
    const int* __restrict__ nodeoff, int nNodes) {
    int gl = threadIdx.x & 1;
    int grp = (int)((blockIdx.x * blockDim.x + threadIdx.x) >> 1);
    int nG = (int)((gridDim.x * blockDim.x) >> 1);
    for (int n = grp; n < nNodes; n += nG) {
        int s0 = nodeoff[n], s1 = nodeoff[n + 1];
        uint4 v = *(const uint4*)(xw2 + ((size_t)n * 9 + 8) * 16 + gl * 8);
        float a[8];
        a[0] = bf2f((unsigned short)v.x); a[1] = bf2f((unsigned short)(v.x >> 16));
        a[2] = bf2f((unsigned short)v.y); a[3] = bf2f((unsigned short)(v.y >> 16));
        a[4] = bf2f((unsigned short)v.z); a[5] = bf2f((unsigned short)(v.z >> 16));
        a[6] = bf2f((unsigned short)v.w); a[7] = bf2f((unsigned short)(v.w >> 16));
        int i = s0;
        for (; i + 4 <= s1; i += 4) {
            int k0 = skey[i], k1 = skey[i + 1], k2 = skey[i + 2], k3 = skey[i + 3];
            uint4 m0 = *(const uint4*)(xw2 + (size_t)k0 * 16 + gl * 8);
            uint4 m1 = *(const uint4*)(xw2 + (size_t)k1 * 16 + gl * 8);
            uint4 m2 = *(const uint4*)(xw2 + (size_t)k2 * 16 + gl * 8);
            uint4 m3 = *(const uint4*)(xw2 + (size_t)k3 * 16 + gl * 8);
            acc8(m0, a); acc8(m1, a); acc8(m2, a); acc8(m3, a);
        }
        for (; i < s1; ++i) {
            uint4 m = *(const uint4*)(xw2 + (size_t)skey[i] * 16 + gl * 8);
            acc8(m, a);
        }
        uint4 p;
        p.x = pk2(a[0], a[1]);
        p.y = pk2(a[2], a[3]);
        p.z = pk2(a[4], a[5]);
        p.w = pk2(a[6], a[7]);
        *(uint4*)(xw2 + ((size_t)n * 9 + 8) * 16 + gl * 8) = p;
    }
}

// ---- mean-pool (reads xw2 row 8) with fused boundary binary search
__global__ __launch_bounds__(256) void k_pool(
    const unsigned short* __restrict__ xw2, const int* __restrict__ gid,
    float* __restrict__ out, int nNodes) {
    __shared__ float sm[256];
    __shared__ int bnd[2];
    int g = blockIdx.x;
    int t = threadIdx.x;
    if (t < 2) {
        int target = g + t;
        int lo = 0, hi = nNodes;
        while (lo < hi) {
            int mid = (lo + hi) >> 1;
            if (gid[mid] < target) lo = mid + 1; else hi = mid;
        }
        bnd[t] = lo;
    }
    __syncthreads();
    int s0 = bnd[0], s1 = bnd[1];
    int c = t & 15, idx = t >> 4;
    float acc = 0.f;
    for (int n = s0 + idx; n < s1; n += 16)
        acc += fmaxf(bf2f(xw2[((size_t)n * 9 + 8) * 16 + c]), 0.f);
    sm[t] = acc;
    __syncthreads();
#pragma unroll
    for (int off = 128; off >= 16; off >>= 1) {
        if (t < off) sm[t] += sm[t + off];
        __syncthreads();
    }
    if (t < 16) {
        float cnt = (float)(s1 - s0);
        out[g * 16 + t] = sm[t] / fmaxf(cnt, 1.f);
    }
}

extern "C" void kernel_launch(void* const* d_in, const int* in_sizes, int n_in,
                              void* d_out, int out_size, void* d_ws, size_t ws_size,
                              hipStream_t stream) {
    const float* x      = (const float*)d_in[0];
    const int*   src    = (const int*)d_in[1];
    const int*   dst    = (const int*)d_in[2];
    const int*   et     = (const int*)d_in[3];
    const int*   gid    = (const int*)d_in[4];
    const float* bases1 = (const float*)d_in[5];
    const float* coeff1 = (const float*)d_in[6];
    const float* wself1 = (const float*)d_in[7];
    const float* bias1  = (const float*)d_in[8];
    const float* bases2 = (const float*)d_in[9];
    const float* coeff2 = (const float*)d_in[10];
    const float* wself2 = (const float*)d_in[11];
    const float* bias2  = (const float*)d_in[12];
    float* out = (float*)d_out;

    int nNodes = in_sizes[0] / 64;
    int nE = in_sizes[1];
    int nBins = (nNodes + 255) >> 8;
    int nBh = nBins * NBLK;

    char* ws = (char*)d_ws;
    unsigned short* W1f  = (unsigned short*)(ws);
    unsigned short* W2f  = (unsigned short*)(ws + 65536);
    unsigned short* W1sf = (unsigned short*)(ws + 81920);
    unsigned short* W2sf = (unsigned short*)(ws + 90112);
    int*   payload = (int*)(ws + 92160);
    int*   skey    = (int*)(ws + 4092160);
    int*   nodeoff = (int*)(ws + 8092160);
    int*   bh      = (int*)(ws + 8492288);
    int*   bhs     = (int*)(ws + 8892672);
    int*   btot    = (int*)(ws + 9293056);
    int*   boff    = (int*)(ws + 9295104);
    unsigned short* xw1 = (unsigned short*)(ws + 9297152);
    unsigned short* xw2 = (unsigned short*)(ws + 124497152);

    int tiles = (nNodes + 15) / 16;
    int xwb = (tiles + 3) / 4;
    int f1b = (nNodes + 63) / 64;
    int scb = (nBh + 255) / 256;

    hipLaunchKernelGGL(k_bhist_w, dim3(NBLK + 8), dim3(256), 0, stream,
                       dst, bh, nE, nBins,
                       bases1, coeff1, bases2, coeff2, wself1, wself2,
                       W1f, W2f, W1sf, W2sf);
    hipLaunchKernelGGL(k_scanblk, dim3(scb), dim3(256), 0, stream,
                       bh, bhs, btot, nBh);
    hipLaunchKernelGGL(k_scantop, dim3(1), dim3(512), 0, stream, btot, boff, scb);
    hipLaunchKernelGGL(k_scanadd2, dim3(scb), dim3(256), 0, stream,
                       bhs, boff, nBh);
    hipLaunchKernelGGL(k_bscat, dim3(NBLK), dim3(256), 0, stream,
                       dst, src, et, bhs, payload, nE, nBins);
    hipLaunchKernelGGL(k_brefine, dim3(nBins), dim3(256), 0, stream,
                       payload, bhs, skey, nodeoff, nE, nBins, nNodes);
    hipLaunchKernelGGL(k_xw1, dim3(xwb), dim3(256), 0, stream,
                       x, W1f, W1sf, bias1, xw1, nNodes);
    hipLaunchKernelGGL(k_f1, dim3(f1b), dim3(256), 0, stream,
                       xw1, skey, nodeoff, W2f, W2sf, bias2, xw2, nNodes);
    hipLaunchKernelGGL(k_seg2f, dim3(1024), dim3(256), 0, stream,
                       xw2, skey, nodeoff, nNodes);
    hipLaunchKernelGGL(k_pool, dim3(64), dim3(256), 0, stream,
                       xw2, gid, out, nNodes);
}

// Round 17
// 167.218 us; speedup vs baseline: 1.9623x; 1.0592x over previous
//
#include <hip/hip_runtime.h>

// ---------------------------------------------------------------------------
// RGCN (basis decomposition, 2 layers) + mean-pool.  v17 = v16 rescheduled:
//  - mega-kernel overlaps bscat (blocks 0..255) with xw1 (blocks 256..)
//    -- independent work, scatter hides under the MFMA write stream
//  - k_scanadd2 deleted (boff added inline in bscat cursors / brefine bounds)
//  - launches 10 -> 8.  All compute bodies identical to v16.
//
// ws layout (bytes):
//   W1f     us[8*4096]   @ 0          B-frags of W1 (bf16)
//   W2f     us[8*1024]   @ 65536
//   W1sf    us[4096]     @ 81920      wself1 frags
//   W2sf    us[1024]     @ 90112      wself2 frags
//   payload int[E]       @ 92160
//   skey    int[E]       @ 4092160    src*9+et, dst-sorted
//   nodeoff int[N+1]     @ 8092160
//   bh      int[nBh]     @ 8492288    (nBh = nBins*256 = 100096 -> 400384 B)
//   bhs     int[nBh]     @ 8892672    (400384 B)
//   btot    int[512]     @ 9293056
//   boff    int[512]     @ 9295104
//   xw1     us[N*9*64]   @ 9297152    (115.2 MB)
//   xw2     us[N*9*16]   @ 124497152  (28.8 MB; row 8 = final agg2)
// NEED ~153.3 MB (ws proven >= 166 MB in rounds 5-8)
// ---------------------------------------------------------------------------

typedef __attribute__((ext_vector_type(8))) short bf16x8;
typedef __attribute__((ext_vector_type(4))) float f32x4;

#define NBLK 256   // blocks for bucket counting sort

__device__ __forceinline__ unsigned short f2bf(float f) {
    unsigned u = __float_as_uint(f);
    unsigned r = u + 0x7FFFu + ((u >> 16) & 1u);   // RNE
    return (unsigned short)(r >> 16);
}

__device__ __forceinline__ float bf2f(unsigned short u) {
    return __uint_as_float(((unsigned)u) << 16);
}

__device__ __forceinline__ unsigned pk2(float lo, float hi) {
    unsigned r;
    asm("v_cvt_pk_bf16_f32 %0, %1, %2" : "=v"(r) : "v"(lo), "v"(hi));
    return r;
}

union cv16 { uint4 u; bf16x8 b; };

__device__ __forceinline__ void acc8(uint4 m, float* a) {
    a[0] += bf2f((unsigned short)m.x); a[1] += bf2f((unsigned short)(m.x >> 16));
    a[2] += bf2f((unsigned short)m.y); a[3] += bf2f((unsigned short)(m.y >> 16));
    a[4] += bf2f((unsigned short)m.z); a[5] += bf2f((unsigned short)(m.z >> 16));
    a[6] += bf2f((unsigned short)m.w); a[7] += bf2f((unsigned short)(m.w >> 16));
}

// ---- fused: blocks 0..NBLK-1 = dst>>8 histogram; blocks NBLK.. = weights
__global__ __launch_bounds__(256) void k_bhist_w(
    const int* __restrict__ dst, int* __restrict__ bh, int nE, int nBins,
    const float* __restrict__ bases1, const float* __restrict__ coeff1,
    const float* __restrict__ bases2, const float* __restrict__ coeff2,
    const float* __restrict__ wself1, const float* __restrict__ wself2,
    unsigned short* __restrict__ W1f, unsigned short* __restrict__ W2f,
    unsigned short* __restrict__ W1sf, unsigned short* __restrict__ W2sf) {
    if (blockIdx.x >= NBLK) {
        int r = blockIdx.x - NBLK;
        int tid = threadIdx.x;
        float c1[8], c2[8];
#pragma unroll
        for (int b = 0; b < 8; ++b) { c1[b] = coeff1[r * 8 + b]; c2[b] = coeff2[r * 8 + b]; }
        for (int idx = tid; idx < 4096; idx += 256) {
            int j = idx & 7, lane = (idx >> 3) & 63, nt = (idx >> 9) & 3, kt = idx >> 11;
            int i = kt * 32 + ((lane >> 4) << 3) + j;
            int jo = nt * 16 + (lane & 15);
            float s = 0.f;
#pragma unroll
            for (int b = 0; b < 8; ++b) s = fmaf(c1[b], bases1[b * 4096 + i * 64 + jo], s);
            W1f[r * 4096 + idx] = f2bf(s);
            if (r == 0) W1sf[idx] = f2bf(wself1[i * 64 + jo]);
        }
        for (int idx = tid; idx < 1024; idx += 256) {
            int j = idx & 7, lane = (idx >> 3) & 63, kt = idx >> 9;
            int i = kt * 32 + ((lane >> 4) << 3) + j;
            int jo = lane & 15;
            float s = 0.f;
#pragma unroll
            for (int b = 0; b < 8; ++b) s = fmaf(c2[b], bases2[b * 1024 + i * 16 + jo], s);
            W2f[r * 1024 + idx] = f2bf(s);
            if (r == 0) W2sf[idx] = f2bf(wself2[i * 16 + jo]);
        }
        return;
    }
    __shared__ int h[512];
    for (int i = threadIdx.x; i < 512; i += 256) h[i] = 0;
    __syncthreads();
    int blk = blockIdx.x;
    int ech = (nE + NBLK - 1) / NBLK;
    int e0 = blk * ech, e1 = min(e0 + ech, nE);
    for (int e = e0 + threadIdx.x; e < e1; e += 256)
        atomicAdd(&h[dst[e] >> 8], 1);
    __syncthreads();
    for (int t = threadIdx.x; t < nBins; t += 256) bh[t * NBLK + blk] = h[t];
}

// ---- scan chain (boff applied downstream, no scanadd pass)
__global__ __launch_bounds__(256) void k_scanblk(
    const int* __restrict__ in, int* __restrict__ outx,
    int* __restrict__ btot, int n) {
    __shared__ int sm[256];
    int tid = threadIdx.x;
    int i = blockIdx.x * 256 + tid;
    int d = (i < n) ? in[i] : 0;
    sm[tid] = d;
    __syncthreads();
#pragma unroll
    for (int off = 1; off < 256; off <<= 1) {
        int v = (tid >= off) ? sm[tid - off] : 0;
        __syncthreads();
        sm[tid] += v;
        __syncthreads();
    }
    if (i < n) outx[i] = sm[tid] - d;
    if (tid == 255) btot[blockIdx.x] = sm[255];
}

__global__ void k_scantop(const int* __restrict__ btot, int* __restrict__ boff, int nB) {
    __shared__ int sm[512];
    int t = threadIdx.x;
    int d = (t < nB) ? btot[t] : 0;
    sm[t] = d;
    __syncthreads();
#pragma unroll
    for (int off = 1; off < 512; off <<= 1) {
        int v = (t >= off) ? sm[t - off] : 0;
        __syncthreads();
        sm[t] += v;
        __syncthreads();
    }
    if (t < nB) boff[t] = sm[t] - d;
}

// ---- mega: blocks 0..NBLK-1 = bscat (cursors = bhs + boff inline);
//            blocks NBLK..    = xw1 MFMA (weights ready from launch 1)
#define XW1S 44
__global__ __launch_bounds__(256) void k_mega(
    const int* __restrict__ dst, const int* __restrict__ src,
    const int* __restrict__ et, const int* __restrict__ bhs,
    const int* __restrict__ boff, int* __restrict__ payload,
    int nE, int nBins,
    const float* __restrict__ x,
    const unsigned short* __restrict__ W1f,
    const unsigned short* __restrict__ W1sf,
    const float* __restrict__ bias1,
    unsigned short* __restrict__ xw1, int nNodes) {
    __shared__ int cur[512];
    __shared__ unsigned lds[4][16 * XW1S];
    if (blockIdx.x < NBLK) {
        int blk = blockIdx.x;
        for (int t = threadIdx.x; t < nBins; t += 256)
            cur[t] = bhs[t * NBLK + blk] + boff[t];
        __syncthreads();
        int ech = (nE + NBLK - 1) / NBLK;
        int e0 = blk * ech, e1 = min(e0 + ech, nE);
        for (int e = e0 + threadIdx.x; e < e1; e += 256) {
            int d = dst[e];
            int pos = atomicAdd(&cur[d >> 8], 1);
            payload[pos] = ((src[e] * 9 + et[e]) << 8) | (d & 255);
        }
        return;
    }
    int lane = threadIdx.x & 63;
    int wid = (int)(threadIdx.x >> 6);
    int tile = (blockIdx.x - NBLK) * 4 + wid;
    int n0 = tile * 16;
    if (n0 >= nNodes) return;
    int sA = n0 + (lane & 15);
    if (sA >= nNodes) sA = nNodes - 1;
    const float* xrow = x + (size_t)sA * 64 + ((lane >> 4) << 3);
    bf16x8 a[2];
#pragma unroll
    for (int kt = 0; kt < 2; ++kt) {
        f32x4 u0 = *(const f32x4*)(xrow + kt * 32);
        f32x4 u1 = *(const f32x4*)(xrow + kt * 32 + 4);
        cv16 c;
        c.u.x = pk2(u0[0], u0[1]);
        c.u.y = pk2(u0[2], u0[3]);
        c.u.z = pk2(u1[0], u1[1]);
        c.u.w = pk2(u1[2], u1[3]);
        a[kt] = c.b;
    }
    float bj[4];
#pragma unroll
    for (int nt = 0; nt < 4; ++nt) bj[nt] = bias1[nt * 16 + (lane & 15)];
    unsigned* L = lds[wid];
    const int even = !(lane & 1);
    const int cpair = (lane & 14) >> 1;
    int row2 = lane >> 2, ch = lane & 3;
    int nOut = n0 + row2;
    for (int r = 0; r < 9; ++r) {
        const unsigned short* Wf = (r < 8) ? (W1f + r * 4096) : W1sf;
        f32x4 z = {0.f, 0.f, 0.f, 0.f};
        f32x4 acc[4] = {z, z, z, z};
#pragma unroll
        for (int kt = 0; kt < 2; ++kt)
#pragma unroll
            for (int nt = 0; nt < 4; ++nt) {
                bf16x8 b = *(const bf16x8*)(Wf + (kt * 4 + nt) * 512 + lane * 8);
                acc[nt] = __builtin_amdgcn_mfma_f32_16x16x32_bf16(a[kt], b, acc[nt], 0, 0, 0);
            }
        if (r == 8) {
#pragma unroll
            for (int nt = 0; nt < 4; ++nt)
#pragma unroll
                for (int reg = 0; reg < 4; ++reg) acc[nt][reg] += bj[nt];
        }
#pragma unroll
        for (int reg = 0; reg < 4; ++reg) {
            int row = ((lane >> 4) << 2) + reg;
#pragma unroll
            for (int nt = 0; nt < 4; ++nt) {
                float mine = acc[nt][reg];
                float oth = __shfl_xor(mine, 1, 64);
                unsigned pk = even ? pk2(mine, oth) : pk2(oth, mine);
                if (even ? (nt < 2) : (nt >= 2)) L[row * XW1S + cpair + nt * 8] = pk;
            }
        }
        if (nOut < nNodes) {
            uint4 v0 = *(uint4*)&L[row2 * XW1S + ch * 4];
            uint4 v1 = *(uint4*)&L[row2 * XW1S + 16 + ch * 4];
            uint4* mp = (uint4*)(xw1 + ((size_t)nOut * 9 + r) * 64);
            mp[ch] = v0;
            mp[4 + ch] = v1;
        }
    }
}

// ---- per-bucket refine -> per-node CSR (skey, nodeoff); boff inline
__global__ __launch_bounds__(256) void k_brefine(
    const int* __restrict__ payload, const int* __restrict__ bhs,
    const int* __restrict__ boff,
    int* __restrict__ skey, int* __restrict__ nodeoff,
    int nE, int nBins, int nNodes) {
    __shared__ int h[256];
    __shared__ int cur[256];
    __shared__ int sm[256];
    int b = blockIdx.x;
    int e0 = bhs[b * NBLK] + boff[b];
    int e1 = (b + 1 < nBins) ? (bhs[(b + 1) * NBLK] + boff[b + 1]) : nE;
    int t = threadIdx.x;
    h[t] = 0;
    __syncthreads();
    for (int e = e0 + t; e < e1; e += 256)
        atomicAdd(&h[payload[e] & 255], 1);
    __syncthreads();
    int d = h[t];
    sm[t] = d;
    __syncthreads();
#pragma unroll
    for (int off = 1; off < 256; off <<= 1) {
        int v = (t >= off) ? sm[t - off] : 0;
        __syncthreads();
        sm[t] += v;
        __syncthreads();
    }
    int excl = sm[t] - d;
    cur[t] = excl;
    int n = (b << 8) + t;
    if (n < nNodes) nodeoff[n] = e0 + excl;
    __syncthreads();
    for (int e = e0 + t; e < e1; e += 256) {
        int pay = payload[e];
        int pos = atomicAdd(&cur[pay & 255], 1);
        skey[e0 + pos] = pay >> 8;
    }
    if (b == 0 && t == 0) nodeoff[nNodes] = nE;
}

// ---- fused: gather+segsum+relu (h in LDS) then xw2 MFMA; 64 nodes/block
__global__ __launch_bounds__(256) void k_f1(
    const unsigned short* __restrict__ xw1, const int* __restrict__ skey,
    const int* __restrict__ nodeoff,
    const unsigned short* __restrict__ W2f,
    const unsigned short* __restrict__ W2sf,
    const float* __restrict__ bias2,
    unsigned short* __restrict__ xw2, int nNodes) {
    __shared__ uint4 hbuf[64][9];
    __shared__ unsigned tlds[4][16 * 12];
    int t = threadIdx.x;
    int n0blk = blockIdx.x * 64;
    int gl = t & 7;
    int grp = t >> 3;
    for (int pass = 0; pass < 2; ++pass) {
        int nn = pass * 32 + grp;
        int n = n0blk + nn;
        uint4 p = {0, 0, 0, 0};
        if (n < nNodes) {
            int s0 = nodeoff[n], s1 = nodeoff[n + 1];
            uint4 v = *(const uint4*)(xw1 + ((size_t)n * 9 + 8) * 64 + gl * 8);
            float a[8];
            a[0] = bf2f((unsigned short)v.x); a[1] = bf2f((unsigned short)(v.x >> 16));
            a[2] = bf2f((unsigned short)v.y); a[3] = bf2f((unsigned short)(v.y >> 16));
            a[4] = bf2f((unsigned short)v.z); a[5] = bf2f((unsigned short)(v.z >> 16));
            a[6] = bf2f((unsigned short)v.w); a[7] = bf2f((unsigned short)(v.w >> 16));
            int i = s0;
            for (; i + 4 <= s1; i += 4) {
                int k0 = skey[i], k1 = skey[i + 1], k2 = skey[i + 2], k3 = skey[i + 3];
                uint4 m0 = *(const uint4*)(xw1 + (size_t)k0 * 64 + gl * 8);
                uint4 m1 = *(const uint4*)(xw1 + (size_t)k1 * 64 + gl * 8);
                uint4 m2 = *(const uint4*)(xw1 + (size_t)k2 * 64 + gl * 8);
                uint4 m3 = *(const uint4*)(xw1 + (size_t)k3 * 64 + gl * 8);
                acc8(m0, a); acc8(m1, a); acc8(m2, a); acc8(m3, a);
            }
            for (; i < s1; ++i) {
                uint4 m = *(const uint4*)(xw1 + (size_t)skey[i] * 64 + gl * 8);
                acc8(m, a);
            }
#pragma unroll
            for (int q = 0; q < 8; ++q) a[q] = fmaxf(a[q], 0.f);   // relu -> h
            p.x = pk2(a[0], a[1]);
            p.y = pk2(a[2], a[3]);
            p.z = pk2(a[4], a[5]);
            p.w = pk2(a[6], a[7]);
        }
        hbuf[nn][gl] = p;
    }
    __syncthreads();
    int lane = t & 63;
    int w = t >> 6;
    int arow = w * 16 + (lane & 15);
    cv16 c0, c1;
    c0.u = hbuf[arow][lane >> 4];
    c1.u = hbuf[arow][4 + (lane >> 4)];
    bf16x8 a0 = c0.b, a1 = c1.b;
    float bj = bias2[lane & 15];
    unsigned* L = tlds[w];
    const int even = !(lane & 1);
    const int cpair = (lane & 14) >> 1;
    int row2 = lane >> 1, ch = lane & 1;
    int nOut = n0blk + w * 16 + row2;
    for (int r = 0; r < 9; ++r) {
        const unsigned short* Wf = (r < 8) ? (W2f + r * 1024) : W2sf;
        bf16x8 b0 = *(const bf16x8*)(Wf + lane * 8);
        bf16x8 b1 = *(const bf16x8*)(Wf + 512 + lane * 8);
        f32x4 acc = {0.f, 0.f, 0.f, 0.f};
        acc = __builtin_amdgcn_mfma_f32_16x16x32_bf16(a0, b0, acc, 0, 0, 0);
        acc = __builtin_amdgcn_mfma_f32_16x16x32_bf16(a1, b1, acc, 0, 0, 0);
        if (r == 8) {
#pragma unroll
            for (int reg = 0; reg < 4; ++reg) acc[reg] += bj;
        }
#pragma unroll
        for (int reg = 0; reg < 4; ++reg) {
            int row = ((lane >> 4) << 2) + reg;
            float mine = acc[reg];
            float oth = __shfl_xor(mine, 1, 64);
            unsigned pk = even ? pk2(mine, oth) : pk2(oth, mine);
            if (even ? (reg < 2) : (reg >= 2)) L[row * 12 + cpair] = pk;
        }
        if (lane < 32 && nOut < nNodes) {
            uint4 v = *(uint4*)&L[row2 * 12 + ch * 4];
            ((uint4*)(xw2 + ((size_t)nOut * 9 + r) * 16))[ch] = v;
        }
    }
}

// ---- layer2 gather+segsum, in place into xw2 row 8 (2-lane group, unroll-4)
__global__ __launch_bounds__(256) void k_seg2f(
    unsigned short* __restrict__ xw2, const int* __restrict__ skey,
    const int* __restrict__ nodeoff, int nNodes) {
    int gl = threadIdx.x & 1;
    int grp = (int)((blockIdx.x * blockDim.x + threadIdx.x) >> 1);
    int nG = (int)((gridDim.x * blockDim.x) >> 1);
    for (int n = grp; n < nNodes; n += nG) {
        int s0 = nodeoff[n], s1 = nodeoff[n + 1];
        uint4 v = *(const uint4*)(xw2 + ((size_t)n * 9 + 8) * 16 + gl * 8);
        float a[8];
        a[0] = bf2f((unsigned short)v.x); a[1] = bf2f((unsigned short)(v.x >> 16));
        a[2] = bf2f((unsigned short)v.y); a[3] = bf2f((unsigned short)(v.y >> 16));
        a[4] = bf2f((unsigned short)v.z); a[5] = bf2f((unsigned short)(v.z >> 16));
        a[6] = bf2f((unsigned short)v.w); a[7] = bf2f((unsigned short)(v.w >> 16));
        int i = s0;
        for (; i + 4 <= s1; i += 4) {
            int k0 = skey[i], k1 = skey[i + 1], k2 = skey[i + 2], k3 = skey[i + 3];
            uint4 m0 = *(const uint4*)(xw2 + (size_t)k0 * 16 + gl * 8);
            uint4 m1 = *(const uint4*)(xw2 + (size_t)k1 * 16 + gl * 8);
            uint4 m2 = *(const uint4*)(xw2 + (size_t)k2 * 16 + gl * 8);
            uint4 m3 = *(const uint4*)(xw2 + (size_t)k3 * 16 + gl * 8);
            acc8(m0, a); acc8(m1, a); acc8(m2, a); acc8(m3, a);
        }
        for (; i < s1; ++i) {
            uint4 m = *(const uint4*)(xw2 + (size_t)skey[i] * 16 + gl * 8);
            acc8(m, a);
        }
        uint4 p;
        p.x = pk2(a[0], a[1]);
        p.y = pk2(a[2], a[3]);
        p.z = pk2(a[4], a[5]);
        p.w = pk2(a[6], a[7]);
        *(uint4*)(xw2 + ((size_t)n * 9 + 8) * 16 + gl * 8) = p;
    }
}

// ---- mean-pool (reads xw2 row 8) with fused boundary binary search
__global__ __launch_bounds__(256) void k_pool(
    const unsigned short* __restrict__ xw2, const int* __restrict__ gid,
    float* __restrict__ out, int nNodes) {
    __shared__ float sm[256];
    __shared__ int bnd[2];
    int g = blockIdx.x;
    int t = threadIdx.x;
    if (t < 2) {
        int target = g + t;
        int lo = 0, hi = nNodes;
        while (lo < hi) {
            int mid = (lo + hi) >> 1;
            if (gid[mid] < target) lo = mid + 1; else hi = mid;
        }
        bnd[t] = lo;
    }
    __syncthreads();
    int s0 = bnd[0], s1 = bnd[1];
    int c = t & 15, idx = t >> 4;
    float acc = 0.f;
    for (int n = s0 + idx; n < s1; n += 16)
        acc += fmaxf(bf2f(xw2[((size_t)n * 9 + 8) * 16 + c]), 0.f);
    sm[t] = acc;
    __syncthreads();
#pragma unroll
    for (int off = 128; off >= 16; off >>= 1) {
        if (t < off) sm[t] += sm[t + off];
        __syncthreads();
    }
    if (t < 16) {
        float cnt = (float)(s1 - s0);
        out[g * 16 + t] = sm[t] / fmaxf(cnt, 1.f);
    }
}

extern "C" void kernel_launch(void* const* d_in, const int* in_sizes, int n_in,
                              void* d_out, int out_size, void* d_ws, size_t ws_size,
                              hipStream_t stream) {
    const float* x      = (const float*)d_in[0];
    const int*   src    = (const int*)d_in[1];
    const int*   dst    = (const int*)d_in[2];
    const int*   et     = (const int*)d_in[3];
    const int*   gid    = (const int*)d_in[4];
    const float* bases1 = (const float*)d_in[5];
    const float* coeff1 = (const float*)d_in[6];
    const float* wself1 = (const float*)d_in[7];
    const float* bias1  = (const float*)d_in[8];
    const float* bases2 = (const float*)d_in[9];
    const float* coeff2 = (const float*)d_in[10];
    const float* wself2 = (const float*)d_in[11];
    const float* bias2  = (const float*)d_in[12];
    float* out = (float*)d_out;

    int nNodes = in_sizes[0] / 64;
    int nE = in_sizes[1];
    int nBins = (nNodes + 255) >> 8;
    int nBh = nBins * NBLK;

    char* ws = (char*)d_ws;
    unsigned short* W1f  = (unsigned short*)(ws);
    unsigned short* W2f  = (unsigned short*)(ws + 65536);
    unsigned short* W1sf = (unsigned short*)(ws + 81920);
    unsigned short* W2sf = (unsigned short*)(ws + 90112);
    int*   payload = (int*)(ws + 92160);
    int*   skey    = (int*)(ws + 4092160);
    int*   nodeoff = (int*)(ws + 8092160);
    int*   bh      = (int*)(ws + 8492288);
    int*   bhs     = (int*)(ws + 8892672);
    int*   btot    = (int*)(ws + 9293056);
    int*   boff    = (int*)(ws + 9295104);
    unsigned short* xw1 = (unsigned short*)(ws + 9297152);
    unsigned short* xw2 = (unsigned short*)(ws + 124497152);

    int tiles = (nNodes + 15) / 16;
    int xwb = (tiles + 3) / 4;
    int f1b = (nNodes + 63) / 64;
    int scb = (nBh + 255) / 256;

    hipLaunchKernelGGL(k_bhist_w, dim3(NBLK + 8), dim3(256), 0, stream,
                       dst, bh, nE, nBins,
                       bases1, coeff1, bases2, coeff2, wself1, wself2,
                       W1f, W2f, W1sf, W2sf);
    hipLaunchKernelGGL(k_scanblk, dim3(scb), dim3(256), 0, stream,
                       bh, bhs, btot, nBh);
    hipLaunchKernelGGL(k_scantop, dim3(1), dim3(512), 0, stream, btot, boff, scb);
    hipLaunchKernelGGL(k_mega, dim3(NBLK + xwb), dim3(256), 0, stream,
                       dst, src, et, bhs, boff, payload, nE, nBins,
                       x, W1f, W1sf, bias1, xw1, nNodes);
    hipLaunchKernelGGL(k_brefine, dim3(nBins), dim3(256), 0, stream,
                       payload, bhs, boff, skey, nodeoff, nE, nBins, nNodes);
    hipLaunchKernelGGL(k_f1, dim3(f1b), dim3(256), 0, stream,
                       xw1, skey, nodeoff, W2f, W2sf, bias2, xw2, nNodes);
    hipLaunchKernelGGL(k_seg2f, dim3(1024), dim3(256), 0, stream,
                       xw2, skey, nodeoff, nNodes);
    hipLaunchKernelGGL(k_pool, dim3(64), dim3(256), 0, stream,
                       xw2, gid, out, nNodes);
}